// Round 1
// baseline (271.735 us; speedup 1.0000x reference)
//
#include <hip/hip_runtime.h>
#include <math.h>

// Problem constants (fixed by setup_inputs)
#define B_ 8
#define P_ 32
#define S_ 512
#define D_ 64
#define TPE_ 16
#define NEG_INF_ (-1e9f)

// Tiling for the attention GEMM
#define TS_ 128   // s-rows per block tile
#define KC_ 32    // k (t) chunk staged in LDS

// ---------------------------------------------------------------------------
// Kernel 1: per-batch min/max normalize t, scale by elu(alpha*1000)+1, emit
// tpe (B,S,16) PRE-SCALED by 0.5 so that dot(tpe_s, tpe_t) == scores/sqrt(16).
// ---------------------------------------------------------------------------
__global__ void k_tpe(const float* __restrict__ t, const float* __restrict__ alpha_w,
                      float* __restrict__ tpe) {
    int b = blockIdx.x;
    int tid = threadIdx.x; // 256 threads
    __shared__ float smin[256], smax[256];
    float v0 = t[b * S_ + tid];
    float v1 = t[b * S_ + tid + 256];
    smin[tid] = fminf(v0, v1);
    smax[tid] = fmaxf(v0, v1);
    __syncthreads();
    for (int off = 128; off > 0; off >>= 1) {
        if (tid < off) {
            smin[tid] = fminf(smin[tid], smin[tid + off]);
            smax[tid] = fmaxf(smax[tid], smax[tid + off]);
        }
        __syncthreads();
    }
    float tmin = smin[0], tmax = smax[0];
    float aw = alpha_w[0] * 1000.0f;
    float el = aw > 0.0f ? aw : (expf(aw) - 1.0f);   // elu(aw), alpha=1
    float scale = el + 1.0f;
    float inv = scale / (tmax - tmin);

    // div_term[i] = 10000^(-i/8)
    const float divs[8] = {1.0f, 0.31622776601683794f, 0.1f, 0.031622776601683791f,
                           0.01f, 0.0031622776601683794f, 0.001f, 0.00031622776601683794f};
    for (int s = tid; s < S_; s += 256) {
        float tn = (t[b * S_ + s] - tmin) * inv;
        float* o = tpe + (b * S_ + s) * TPE_;
#pragma unroll
        for (int i = 0; i < 8; i++) {
            float ang = tn * divs[i];
            o[2 * i]     = 0.5f * sinf(ang);   // 0.5 factor folds the /sqrt(dk)
            o[2 * i + 1] = 0.5f * cosf(ang);
        }
    }
}

// ---------------------------------------------------------------------------
// Kernel 2: scores[b,s,t] = dot16(tpe[b,s], tpe[b,t])  (already /4-scaled)
// ---------------------------------------------------------------------------
__global__ void k_scores(const float* __restrict__ tpe, float* __restrict__ scores) {
    int s = blockIdx.x;
    int b = blockIdx.y;
    int tid = threadIdx.x; // 256
    __shared__ float q[16];
    if (tid < 16) q[tid] = tpe[(b * S_ + s) * TPE_ + tid];
    __syncthreads();
    for (int tt = tid; tt < S_; tt += 256) {
        const float4* r4 = (const float4*)(tpe + (b * S_ + tt) * TPE_);
        float4 r0 = r4[0], r1 = r4[1], r2 = r4[2], r3 = r4[3];
        float d = q[0] * r0.x + q[1] * r0.y + q[2] * r0.z + q[3] * r0.w
                + q[4] * r1.x + q[5] * r1.y + q[6] * r1.z + q[7] * r1.w
                + q[8] * r2.x + q[9] * r2.y + q[10] * r2.z + q[11] * r2.w
                + q[12] * r3.x + q[13] * r3.y + q[14] * r3.z + q[15] * r3.w;
        scores[(b * S_ + s) * S_ + tt] = d;
    }
}

// ---------------------------------------------------------------------------
// Kernel 3: masked softmax + P@X + blend, per (b, p, s-tile of 128 rows).
// Two-pass softmax: phase A computes per-row max & 1/sum; phase B recomputes
// weights on the fly into LDS tiles and does a register-blocked fp32 GEMM.
// ---------------------------------------------------------------------------
__launch_bounds__(256)
__global__ void k_attn(const float* __restrict__ x, const float* __restrict__ mask,
                       const float* __restrict__ scores, float* __restrict__ out) {
    int tile = blockIdx.x; // 0..3
    int p    = blockIdx.y; // 0..31
    int b    = blockIdx.z; // 0..7
    int tid  = threadIdx.x; // 256

    __shared__ float maskL[S_];            // 2 KB: mask[b,p,:]
    __shared__ float rmax[TS_];            // per-row logit max
    __shared__ float rsumi[TS_];           // per-row 1/sum(exp)
    __shared__ float Xs[KC_][D_];          // 8 KB: X k-chunk
    __shared__ float Ws[TS_][KC_ + 1];     // ~16.9 KB: softmax numerators (padded +1)

    const float* maskBP = mask + (b * P_ + p) * S_;
    const float* xBP    = x + (size_t)(b * P_ + p) * S_ * D_;

    for (int i = tid; i < S_; i += 256) maskL[i] = maskBP[i];
    __syncthreads();

    // ---- Phase A: row stats (max, 1/sum) for the 128 rows of this tile ----
    int wave = tid >> 6, lane = tid & 63;
    for (int r = wave; r < TS_; r += 4) {
        int sg = tile * TS_ + r;
        const float* srow = scores + (size_t)(b * S_ + sg) * S_;
        float lg[8];
        float lmax = -INFINITY;
#pragma unroll
        for (int j = 0; j < 8; j++) {
            int tt = lane + j * 64;
            float sv = srow[tt];
            bool valid = (maskL[tt] + (tt == sg ? 1.0f : 0.0f)) >= 0.5f;
            lg[j] = valid ? sv : NEG_INF_;
            lmax = fmaxf(lmax, lg[j]);
        }
#pragma unroll
        for (int o = 32; o > 0; o >>= 1) lmax = fmaxf(lmax, __shfl_xor(lmax, o, 64));
        float lsum = 0.0f;
#pragma unroll
        for (int j = 0; j < 8; j++) lsum += __expf(lg[j] - lmax);
#pragma unroll
        for (int o = 32; o > 0; o >>= 1) lsum += __shfl_xor(lsum, o, 64);
        if (lane == 0) {
            rmax[r]  = lmax;
            rsumi[r] = 1.0f / lsum;
        }
    }

    // ---- Phase B: GEMM inter = P @ X, register tile 4 s-rows x 8 d-cols ----
    int td = tid & 7;    // d-group: d0 = td*8
    int ts = tid >> 3;   // s-group: s0 = ts*4  (32 groups x 4 rows = 128)
    int d0 = td * 8;
    int s0 = ts * 4;
    float acc[4][8];
#pragma unroll
    for (int r = 0; r < 4; r++)
#pragma unroll
        for (int e = 0; e < 8; e++) acc[r][e] = 0.0f;

    for (int kc = 0; kc < S_; kc += KC_) {
        __syncthreads(); // protect prior iteration's LDS reads (and phase A on iter 0)

        // stage X[kc..kc+32, :] -> Xs (2048 floats, 2 x float4 per thread)
        {
            const float4* xg = (const float4*)(xBP + (size_t)kc * D_);
            float4* xs4 = (float4*)&Xs[0][0];
            xs4[tid]       = xg[tid];
            xs4[tid + 256] = xg[tid + 256];
        }
        // compute softmax numerators Ws[r][tk] = exp(logit - rmax[r])
#pragma unroll
        for (int j = 0; j < 16; j++) {
            int lin = j * 256 + tid;   // 0..4095
            int r   = lin >> 5;        // row in tile
            int tk  = lin & 31;
            int tt  = kc + tk;
            int sg  = tile * TS_ + r;
            float sv = scores[(size_t)(b * S_ + sg) * S_ + tt];
            bool valid = (maskL[tt] + (tt == sg ? 1.0f : 0.0f)) >= 0.5f;
            float lg = valid ? sv : NEG_INF_;
            Ws[r][tk] = __expf(lg - rmax[r]);
        }
        __syncthreads();

#pragma unroll
        for (int kk = 0; kk < KC_; kk++) {
            float4 xa = *(const float4*)&Xs[kk][d0];
            float4 xb = *(const float4*)&Xs[kk][d0 + 4];
            float w0 = Ws[s0 + 0][kk];
            float w1 = Ws[s0 + 1][kk];
            float w2 = Ws[s0 + 2][kk];
            float w3 = Ws[s0 + 3][kk];
            acc[0][0] += w0 * xa.x; acc[0][1] += w0 * xa.y; acc[0][2] += w0 * xa.z; acc[0][3] += w0 * xa.w;
            acc[0][4] += w0 * xb.x; acc[0][5] += w0 * xb.y; acc[0][6] += w0 * xb.z; acc[0][7] += w0 * xb.w;
            acc[1][0] += w1 * xa.x; acc[1][1] += w1 * xa.y; acc[1][2] += w1 * xa.z; acc[1][3] += w1 * xa.w;
            acc[1][4] += w1 * xb.x; acc[1][5] += w1 * xb.y; acc[1][6] += w1 * xb.z; acc[1][7] += w1 * xb.w;
            acc[2][0] += w2 * xa.x; acc[2][1] += w2 * xa.y; acc[2][2] += w2 * xa.z; acc[2][3] += w2 * xa.w;
            acc[2][4] += w2 * xb.x; acc[2][5] += w2 * xb.y; acc[2][6] += w2 * xb.z; acc[2][7] += w2 * xb.w;
            acc[3][0] += w3 * xa.x; acc[3][1] += w3 * xa.y; acc[3][2] += w3 * xa.z; acc[3][3] += w3 * xa.w;
            acc[3][4] += w3 * xb.x; acc[3][5] += w3 * xb.y; acc[3][6] += w3 * xb.z; acc[3][7] += w3 * xb.w;
        }
    }

    // ---- Epilogue: out = m*x + (1-m)*inter, inter = acc * (1/sum) ----
#pragma unroll
    for (int r = 0; r < 4; r++) {
        int sl = s0 + r;
        int sg = tile * TS_ + sl;
        float m  = maskL[sg];
        float ri = rsumi[sl];
        float om = 1.0f - m;
        const float4* xr = (const float4*)(xBP + (size_t)sg * D_ + d0);
        float4 x0 = xr[0], x1 = xr[1];
        float4 o0, o1;
        o0.x = m * x0.x + om * acc[r][0] * ri;
        o0.y = m * x0.y + om * acc[r][1] * ri;
        o0.z = m * x0.z + om * acc[r][2] * ri;
        o0.w = m * x0.w + om * acc[r][3] * ri;
        o1.x = m * x1.x + om * acc[r][4] * ri;
        o1.y = m * x1.y + om * acc[r][5] * ri;
        o1.z = m * x1.z + om * acc[r][6] * ri;
        o1.w = m * x1.w + om * acc[r][7] * ri;
        float4* orow = (float4*)(out + ((size_t)(b * P_ + p) * S_ + sg) * D_ + d0);
        orow[0] = o0;
        orow[1] = o1;
    }
}

// ---------------------------------------------------------------------------
extern "C" void kernel_launch(void* const* d_in, const int* in_sizes, int n_in,
                              void* d_out, int out_size, void* d_ws, size_t ws_size,
                              hipStream_t stream) {
    const float* t       = (const float*)d_in[0]; // (B,S)
    const float* x       = (const float*)d_in[1]; // (B,P,S,D)
    const float* mask    = (const float*)d_in[2]; // (B,P,S)
    const float* alpha_w = (const float*)d_in[3]; // (1,1)
    float* out = (float*)d_out;

    // ws layout: tpe (B*S*16 floats) | scores (B*S*S floats) -> ~8.6 MB total
    float* ws     = (float*)d_ws;
    float* tpe    = ws;
    float* scores = ws + (size_t)B_ * S_ * TPE_;

    k_tpe<<<dim3(B_), dim3(256), 0, stream>>>(t, alpha_w, tpe);
    k_scores<<<dim3(S_, B_), dim3(256), 0, stream>>>(tpe, scores);
    k_attn<<<dim3(S_ / TS_, P_, B_), dim3(256), 0, stream>>>(x, mask, scores, out);
}

// Round 2
// 185.364 us; speedup vs baseline: 1.4660x; 1.4660x over previous
//
#include <hip/hip_runtime.h>
#include <math.h>

// Problem constants (fixed by setup_inputs)
#define B_ 8
#define P_ 32
#define S_ 512
#define D_ 64
#define TPE_ 16

#define KC_ 32    // key chunk staged in LDS
#define TQ_ 96    // query rows per pass (3 rows/thread x 32 row-groups)

// ---------------------------------------------------------------------------
// Kernel 1 (fused): per-batch min/max normalize t, elu scale, tpe in LDS,
// scores[b, s0..s0+16, 0..512) = dot16(tpe_s, tpe_t)  (pre-scaled by 1/4).
// Grid: (S/16, B) = 256 blocks.
// ---------------------------------------------------------------------------
__launch_bounds__(256)
__global__ void k_scores2(const float* __restrict__ t, const float* __restrict__ alpha_w,
                          float* __restrict__ scores) {
    const int b = blockIdx.y;
    const int s0 = blockIdx.x * 16;
    const int tid = threadIdx.x;
    const int lane = tid & 63, wave = tid >> 6;

    __shared__ float tl[S_];
    __shared__ float red[8];
    __shared__ float tpeL[S_][20];   // padded 16->20 words: row stride 20 mod 32 cycles 8 groups

    float v0 = t[b * S_ + tid];
    float v1 = t[b * S_ + tid + 256];
    tl[tid] = v0; tl[tid + 256] = v1;
    float mn = fminf(v0, v1), mx = fmaxf(v0, v1);
#pragma unroll
    for (int o = 32; o > 0; o >>= 1) {
        mn = fminf(mn, __shfl_xor(mn, o, 64));
        mx = fmaxf(mx, __shfl_xor(mx, o, 64));
    }
    if (lane == 0) { red[wave] = mn; red[4 + wave] = mx; }
    __syncthreads();
    mn = fminf(fminf(red[0], red[1]), fminf(red[2], red[3]));
    mx = fmaxf(fmaxf(red[4], red[5]), fmaxf(red[6], red[7]));

    float aw = alpha_w[0] * 1000.0f;
    float el = aw > 0.0f ? aw : (__expf(aw) - 1.0f);   // elu, alpha=1
    float inv = (el + 1.0f) / (mx - mn);

    const float divs[8] = {1.0f, 0.31622776601683794f, 0.1f, 0.031622776601683791f,
                           0.01f, 0.0031622776601683794f, 0.001f, 0.00031622776601683794f};
    // 512 rows x 8 freqs = 4096 items / 256 threads = 16 each
#pragma unroll
    for (int it = 0; it < 16; it++) {
        int idx = it * 256 + tid;
        int s = idx >> 3, f = idx & 7;
        float tn = (tl[s] - mn) * inv;
        float ang = tn * divs[f];
        tpeL[s][2 * f]     = 0.5f * __sinf(ang);   // 0.5^2 folds /sqrt(16)
        tpeL[s][2 * f + 1] = 0.5f * __cosf(ang);
    }
    __syncthreads();

    const int sl = tid >> 4;        // 0..15 local row
    const int tt0 = tid & 15;
    float q[16];
#pragma unroll
    for (int i = 0; i < 16; i++) q[i] = tpeL[s0 + sl][i];
    float* orow = scores + ((size_t)(b * S_) + s0 + sl) * S_;
#pragma unroll 4
    for (int k = 0; k < 32; k++) {
        int tt = tt0 + k * 16;
        const float4* r4 = (const float4*)&tpeL[tt][0];
        float4 r0 = r4[0], r1 = r4[1], r2 = r4[2], r3 = r4[3];
        float d = q[0] * r0.x + q[1] * r0.y + q[2] * r0.z + q[3] * r0.w
                + q[4] * r1.x + q[5] * r1.y + q[6] * r1.z + q[7] * r1.w
                + q[8] * r2.x + q[9] * r2.y + q[10] * r2.z + q[11] * r2.w
                + q[12] * r3.x + q[13] * r3.y + q[14] * r3.z + q[15] * r3.w;
        orow[tt] = d;
    }
}

// ---------------------------------------------------------------------------
// Kernel 2: compacted masked softmax + P@X + blend.
//   m=1 rows: out = x (copy).  m=0 rows: softmax over keys {t: m[t]=1} U {s}.
//   scores in [-2,2] -> fixed softmax shift of 2 (no max pass).
// Grid: (4, P, B). Each block: quarter of copies + quarter of queries.
// ---------------------------------------------------------------------------
__launch_bounds__(256)
__global__ void k_attn2(const float* __restrict__ x, const float* __restrict__ mask,
                        const float* __restrict__ scores, float* __restrict__ out) {
    const int tile = blockIdx.x;
    const int p = blockIdx.y, b = blockIdx.z;
    const int tid = threadIdx.x;
    const int lane = tid & 63, wave = tid >> 6;

    __shared__ float maskL[S_];
    __shared__ short kidxL[S_];
    __shared__ short qidxL[S_];
    __shared__ int cntS[2];
    __shared__ float rsum[TQ_];
    __shared__ float Xs[KC_][D_];
    __shared__ float Ws[TQ_][KC_ + 1];

    const size_t bp = (size_t)(b * P_ + p);
    const float* maskBP = mask + bp * S_;
    const float4* x4 = (const float4*)x + bp * S_ * (D_ / 4);
    float4* out4 = (float4*)out + bp * S_ * (D_ / 4);
    const float* scB = scores + (size_t)b * S_ * S_;

    for (int i = tid; i < S_; i += 256) maskL[i] = maskBP[i];
    __syncthreads();

    // build compacted key / query index lists (wave 0, ballot prefix)
    if (wave == 0) {
        int nk = 0, nq = 0;
        for (int c = 0; c < 8; c++) {
            int tt = c * 64 + lane;
            bool isk = maskL[tt] >= 0.5f;
            unsigned long long bm = __ballot(isk);
            int pb = __popcll(bm & ((1ull << lane) - 1ull));
            if (isk) kidxL[nk + pb] = (short)tt;
            else     qidxL[nq + lane - pb] = (short)tt;
            int c1 = __popcll(bm);
            nk += c1; nq += 64 - c1;
        }
        if (lane == 0) { cntS[0] = nk; cntS[1] = nq; }
    }
    __syncthreads();
    const int NK = cntS[0], NQ = cntS[1];

    // ---- copy phase: m=1 rows, this block's quarter ----
    {
        int nkq = (NK + 3) >> 2;
        int j0 = tile * nkq, j1 = min(NK, j0 + nkq);
        for (int e = j0 * 16 + tid; e < j1 * 16; e += 256) {
            int s = kidxL[e >> 4];
            int d4 = e & 15;
            out4[s * 16 + d4] = x4[s * 16 + d4];
        }
    }

    // ---- query phase: this block's quarter of the compacted query list ----
    const int qq = (NQ + 3) >> 2;
    const int qb0 = tile * qq;
    const int qend = min(NQ, qb0 + qq);
    const int rg = tid >> 3;          // row group 0..31
    const int d0 = (tid & 7) * 8;     // 8 d-columns per thread
    const int tk = tid & 31;
    const int wr0 = tid >> 5;         // 0..7 (Ws row stride base)

    for (int q0 = qb0; q0 < qend; q0 += TQ_) {   // 1 pass in practice
        const int rows = min(TQ_, qend - q0);
        __syncthreads();   // protect rsum/Xs/Ws from previous pass

        // Phase A: row denominators (masked sum, fixed shift 2)
        for (int r = wave; r < rows; r += 4) {
            int sg = qidxL[q0 + r];
            const float* srow = scB + (size_t)sg * S_;
            float lsum = 0.0f;
#pragma unroll
            for (int j = 0; j < 8; j++) {
                int tt = lane + j * 64;
                lsum += maskL[tt] * __expf(srow[tt] - 2.0f);
            }
#pragma unroll
            for (int o = 32; o > 0; o >>= 1) lsum += __shfl_xor(lsum, o, 64);
            if (lane == 0) rsum[r] = lsum;
        }

        float acc[3][8];
#pragma unroll
        for (int i = 0; i < 3; i++)
#pragma unroll
            for (int e = 0; e < 8; e++) acc[i][e] = 0.0f;

        const int nch = (NK + KC_ - 1) / KC_;
        for (int c = 0; c < nch; c++) {
            const int kc = c * KC_;
            __syncthreads();
            // stage gathered X keys
#pragma unroll
            for (int h = 0; h < 2; h++) {
                int i4 = tid + h * 256;
                int kk = i4 >> 4, d4 = i4 & 15;
                int kt = kc + kk;
                int src = kidxL[kt < NK ? kt : 0];
                ((float4*)Xs)[i4] = x4[src * 16 + d4];
            }
            // softmax numerators for this key chunk
            {
                int kt = kc + tk;
                bool kv = kt < NK;
                int kcol = kidxL[kv ? kt : 0];
#pragma unroll
                for (int j = 0; j < TQ_ / 8; j++) {
                    int rr = wr0 + 8 * j;
                    float w = 0.0f;
                    if (kv && rr < rows) {
                        int sg = qidxL[q0 + rr];
                        w = __expf(scB[(size_t)sg * S_ + kcol] - 2.0f);
                    }
                    Ws[rr][tk] = w;
                }
            }
            __syncthreads();
#pragma unroll
            for (int kk = 0; kk < KC_; kk++) {
                float4 xa = *(const float4*)&Xs[kk][d0];
                float4 xb = *(const float4*)&Xs[kk][d0 + 4];
#pragma unroll
                for (int i = 0; i < 3; i++) {
                    float w = Ws[rg + 32 * i][kk];
                    acc[i][0] += w * xa.x; acc[i][1] += w * xa.y;
                    acc[i][2] += w * xa.z; acc[i][3] += w * xa.w;
                    acc[i][4] += w * xb.x; acc[i][5] += w * xb.y;
                    acc[i][6] += w * xb.z; acc[i][7] += w * xb.w;
                }
            }
        }

        __syncthreads();   // rsum visibility (covers nch==0)

        // epilogue: add self term, normalize, store
#pragma unroll
        for (int i = 0; i < 3; i++) {
            int r = rg + 32 * i;
            if (r < rows) {
                int sg = qidxL[q0 + r];
                float ws = __expf(scB[(size_t)sg * S_ + sg] - 2.0f);
                float inv = 1.0f / (rsum[r] + ws);
                float4 xv0 = x4[sg * 16 + (d0 >> 2)];
                float4 xv1 = x4[sg * 16 + (d0 >> 2) + 1];
                float4 o0, o1;
                o0.x = (acc[i][0] + ws * xv0.x) * inv;
                o0.y = (acc[i][1] + ws * xv0.y) * inv;
                o0.z = (acc[i][2] + ws * xv0.z) * inv;
                o0.w = (acc[i][3] + ws * xv0.w) * inv;
                o1.x = (acc[i][4] + ws * xv1.x) * inv;
                o1.y = (acc[i][5] + ws * xv1.y) * inv;
                o1.z = (acc[i][6] + ws * xv1.z) * inv;
                o1.w = (acc[i][7] + ws * xv1.w) * inv;
                out4[sg * 16 + (d0 >> 2)] = o0;
                out4[sg * 16 + (d0 >> 2) + 1] = o1;
            }
        }
    }
}

// ---------------------------------------------------------------------------
extern "C" void kernel_launch(void* const* d_in, const int* in_sizes, int n_in,
                              void* d_out, int out_size, void* d_ws, size_t ws_size,
                              hipStream_t stream) {
    const float* t       = (const float*)d_in[0]; // (B,S)
    const float* x       = (const float*)d_in[1]; // (B,P,S,D)
    const float* mask    = (const float*)d_in[2]; // (B,P,S)
    const float* alpha_w = (const float*)d_in[3]; // (1,1)
    float* out = (float*)d_out;

    float* scores = (float*)d_ws;   // B*S*S floats = 8 MB

    k_scores2<<<dim3(S_ / 16, B_), dim3(256), 0, stream>>>(t, alpha_w, scores);
    k_attn2<<<dim3(4, P_, B_), dim3(256), 0, stream>>>(x, mask, scores, out);
}

// Round 3
// 142.632 us; speedup vs baseline: 1.9051x; 1.2996x over previous
//
#include <hip/hip_runtime.h>
#include <math.h>

#define B_ 8
#define P_ 32
#define S_ 512
#define D_ 64

typedef __attribute__((ext_vector_type(8))) short short8;
typedef __attribute__((ext_vector_type(4))) float f32x4;

static __device__ inline unsigned short f2bf(float f) {
    // round-to-nearest-even fp32 -> bf16 (finite inputs only)
    unsigned u = __float_as_uint(f);
    unsigned r = (u + 0x7FFFu + ((u >> 16) & 1u)) >> 16;
    return (unsigned short)r;
}
static __device__ inline float bf2f(unsigned short s) {
    return __uint_as_float(((unsigned)s) << 16);
}

// ---------------------------------------------------------------------------
// Kernel 1: tpe (B,S,16) fp32 to global. Pre-scaled by 0.5 so dot = score/4.
// ---------------------------------------------------------------------------
__global__ void k_tpe(const float* __restrict__ t, const float* __restrict__ alpha_w,
                      float* __restrict__ tpeG) {
    int b = blockIdx.x;
    int tid = threadIdx.x, lane = tid & 63, wave = tid >> 6;
    __shared__ float red[8];
    float v0 = t[b * S_ + tid];
    float v1 = t[b * S_ + tid + 256];
    float mn = fminf(v0, v1), mx = fmaxf(v0, v1);
#pragma unroll
    for (int o = 32; o > 0; o >>= 1) {
        mn = fminf(mn, __shfl_xor(mn, o, 64));
        mx = fmaxf(mx, __shfl_xor(mx, o, 64));
    }
    if (lane == 0) { red[wave] = mn; red[4 + wave] = mx; }
    __syncthreads();
    mn = fminf(fminf(red[0], red[1]), fminf(red[2], red[3]));
    mx = fmaxf(fmaxf(red[4], red[5]), fmaxf(red[6], red[7]));

    float aw = alpha_w[0] * 1000.0f;
    float el = aw > 0.0f ? aw : (__expf(aw) - 1.0f);
    float inv = (el + 1.0f) / (mx - mn);

    const float divs[8] = {1.0f, 0.31622776601683794f, 0.1f, 0.031622776601683791f,
                           0.01f, 0.0031622776601683794f, 0.001f, 0.00031622776601683794f};
    for (int s = tid; s < S_; s += 256) {
        float tn = (t[b * S_ + s] - mn) * inv;
        float o[16];
#pragma unroll
        for (int i = 0; i < 8; i++) {
            float ang = tn * divs[i];
            o[2 * i]     = 0.5f * __sinf(ang);
            o[2 * i + 1] = 0.5f * __cosf(ang);
        }
        float4* og = (float4*)(tpeG + ((size_t)b * S_ + s) * 16);
#pragma unroll
        for (int i = 0; i < 4; i++)
            og[i] = make_float4(o[4 * i], o[4 * i + 1], o[4 * i + 2], o[4 * i + 3]);
    }
}

// ---------------------------------------------------------------------------
// Kernel 2: E16[b,s,t] = bf16(exp(dot16(tpe_s,tpe_t) - 2)). Grid (S/4, B).
// One wave per query row; key pairs per lane -> packed dword stores.
// ---------------------------------------------------------------------------
__launch_bounds__(256)
__global__ void k_scoresE(const float* __restrict__ tpeG, unsigned short* __restrict__ E16) {
    int b = blockIdx.y;
    int lane = threadIdx.x & 63, wave = threadIdx.x >> 6;
    int r = blockIdx.x * 4 + wave;
    const float* tb = tpeG + (size_t)b * S_ * 16;

    float q[16];
    {
        const float4* q4 = (const float4*)(tb + (size_t)r * 16);
#pragma unroll
        for (int i = 0; i < 4; i++) {
            float4 v = q4[i];
            q[4 * i] = v.x; q[4 * i + 1] = v.y; q[4 * i + 2] = v.z; q[4 * i + 3] = v.w;
        }
    }
    unsigned* Erow = (unsigned*)(E16 + ((size_t)(b * S_ + r)) * S_);
#pragma unroll
    for (int j = 0; j < 4; j++) {
        int pp = lane + 64 * j;
        int c0 = pp * 2;
        const float4* k0 = (const float4*)(tb + (size_t)c0 * 16);
        const float4* k1 = (const float4*)(tb + (size_t)(c0 + 1) * 16);
        float d0 = 0.0f, d1 = 0.0f;
#pragma unroll
        for (int i = 0; i < 4; i++) {
            float4 a = k0[i], c = k1[i];
            d0 += q[4 * i] * a.x + q[4 * i + 1] * a.y + q[4 * i + 2] * a.z + q[4 * i + 3] * a.w;
            d1 += q[4 * i] * c.x + q[4 * i + 1] * c.y + q[4 * i + 2] * c.z + q[4 * i + 3] * c.w;
        }
        unsigned short e0 = f2bf(__expf(d0 - 2.0f));
        unsigned short e1 = f2bf(__expf(d1 - 2.0f));
        Erow[pp] = (unsigned)e0 | ((unsigned)e1 << 16);
    }
}

// ---------------------------------------------------------------------------
// Kernel 3: MFMA attention. Grid (2, P, B), 256 threads (4 waves).
//   copy rows (mask=1): out = x.  query rows (mask=0): softmax via E16.
//   B-operand: XsT[n][k] bf16, n=0..63 masked x cols, n=64 mask (denominator),
//   rows 65..79 zero. A-operand: E16 rows loaded direct from global.
// ---------------------------------------------------------------------------
#define NSTRIDE 40   // shorts per XsT row (80 B: 16B-aligned b128, <=4-way bank)
__launch_bounds__(256)
__global__ void k_attn3(const float* __restrict__ x, const float* __restrict__ mask,
                        const unsigned short* __restrict__ E16, float* __restrict__ out) {
    const int tile = blockIdx.x;          // 0..1 (query/copy halves)
    const int p = blockIdx.y, b = blockIdx.z;
    const int tid = threadIdx.x, lane = tid & 63, wave = tid >> 6;
    const int quad = lane >> 4, nlane = lane & 15;

    __shared__ float maskL[S_];
    __shared__ short kidxL[S_], qidxL[S_];
    __shared__ int cntS[2];
    __shared__ unsigned short XsT[2][80][NSTRIDE];

    const size_t bp = (size_t)(b * P_ + p);
    const float* maskBP = mask + bp * S_;
    const float* xBP = x + bp * S_ * D_;
    float* outBP = out + bp * S_ * D_;
    const float4* x4 = (const float4*)xBP;
    float4* out4 = (float4*)outBP;
    const unsigned short* Eb = E16 + (size_t)b * S_ * S_;

    for (int i = tid; i < S_; i += 256) maskL[i] = maskBP[i];
    __syncthreads();

    // compacted key (mask=1) / query (mask=0) lists
    if (wave == 0) {
        int nk = 0, nq = 0;
        for (int c = 0; c < 8; c++) {
            int tt = c * 64 + lane;
            bool isk = maskL[tt] >= 0.5f;
            unsigned long long bm = __ballot(isk);
            int pb = __popcll(bm & ((1ull << lane) - 1ull));
            if (isk) kidxL[nk + pb] = (short)tt;
            else     qidxL[nq + lane - pb] = (short)tt;
            int c1 = __popcll(bm);
            nk += c1; nq += 64 - c1;
        }
        if (lane == 0) { cntS[0] = nk; cntS[1] = nq; }
    }
    // zero XsT rows 65..79 (both buffers) once
    for (int i = tid; i < 2 * 15 * NSTRIDE; i += 256) {
        int bb = i / (15 * NSTRIDE);
        int rem = i % (15 * NSTRIDE);
        XsT[bb][65 + rem / NSTRIDE][rem % NSTRIDE] = 0;
    }
    __syncthreads();
    const int NK = cntS[0], NQ = cntS[1];

    // ---- copy phase: half of the mask=1 rows ----
    {
        int nkq = (NK + 1) >> 1;
        int j0 = tile * nkq, j1 = min(NK, j0 + nkq);
        for (int e = j0 * 16 + tid; e < j1 * 16; e += 256) {
            int s = kidxL[e >> 4];
            int d4 = e & 15;
            out4[s * 16 + d4] = x4[s * 16 + d4];
        }
    }

    // ---- query phase ----
    const int qq = (NQ + 1) >> 1;
    const int qb0 = tile * qq;
    const int rows = min(NQ, qb0 + qq) - qb0;
    const int NT = (rows + 15) >> 4;

    const int c64 = tid & 63;       // x column this thread stages
    const int kg = tid >> 6;        // key subgroup (8 keys each)
    const float* xcol = xBP + c64;

    auto loadx = [&](int kcv, float* xr) {
        const float* base = xcol + (size_t)(kcv + kg * 8) * D_;
#pragma unroll
        for (int i = 0; i < 8; i++) xr[i] = base[i * D_];
    };
    auto stage = [&](int bufi, int kcv, const float* xr) {
        short8 w8;
#pragma unroll
        for (int i = 0; i < 8; i++) {
            float mv = maskL[kcv + kg * 8 + i];
            w8[i] = (short)f2bf(xr[i] * mv);
        }
        *(short8*)&XsT[bufi][c64][kg * 8] = w8;
        if (tid < 32) XsT[bufi][64][tid] = f2bf(maskL[kcv + tid]);
    };

    for (int tb = 0; tb < NT; tb += 12) {
        // per-wave tiles: ti = tb + wave + 4*i, i<3
        const unsigned short* Arow[3];
        int tiv[3];
#pragma unroll
        for (int i = 0; i < 3; i++) {
            int ti = tb + wave + 4 * i;
            tiv[i] = ti;
            int rowl = ti * 16 + nlane;
            int rr = rowl < rows ? rowl : 0;
            int sg = qidxL[qb0 + rr];
            Arow[i] = Eb + (size_t)sg * S_;
        }
        f32x4 acc[3][5];
#pragma unroll
        for (int i = 0; i < 3; i++)
#pragma unroll
            for (int ct = 0; ct < 5; ct++) acc[i][ct] = (f32x4){0.f, 0.f, 0.f, 0.f};

        float xr[8];
        loadx(0, xr);
        stage(0, 0, xr);

        for (int c = 0; c < 16; c++) {
            const int kc = c * 32;
            __syncthreads();                       // buffer c&1 ready
            float xrn[8];
            if (c < 15) loadx(kc + 32, xrn);       // prefetch next chunk

            short8 bf[5];
#pragma unroll
            for (int ct = 0; ct < 5; ct++)
                bf[ct] = *(const short8*)&XsT[c & 1][ct * 16 + nlane][quad * 8];

#pragma unroll
            for (int i = 0; i < 3; i++) {
                if (tiv[i] < NT) {
                    short8 a = *(const short8*)(Arow[i] + kc + quad * 8);
#pragma unroll
                    for (int ct = 0; ct < 5; ct++)
                        acc[i][ct] = __builtin_amdgcn_mfma_f32_16x16x32_bf16(a, bf[ct], acc[i][ct], 0, 0, 0);
                }
            }
            if (c < 15) stage((c + 1) & 1, kc + 32, xrn);
        }

        // ---- epilogue ----
#pragma unroll
        for (int i = 0; i < 3; i++) {
            if (tiv[i] >= NT) continue;
#pragma unroll
            for (int reg = 0; reg < 4; reg++) {
                int rowl = tiv[i] * 16 + quad * 4 + reg;
                float den = __shfl(acc[i][4][reg], lane & 48, 64);  // col 0 of tile 4
                if (rowl < rows) {
                    int sg = qidxL[qb0 + rowl];
                    float ws = bf2f(Eb[(size_t)sg * S_ + sg]);
                    float inv = 1.0f / (den + ws);
#pragma unroll
                    for (int ct = 0; ct < 4; ct++) {
                        int col = ct * 16 + nlane;
                        float xv = xBP[(size_t)sg * D_ + col];
                        outBP[(size_t)sg * D_ + col] = (acc[i][ct][reg] + ws * xv) * inv;
                    }
                }
            }
        }
    }
}

// ---------------------------------------------------------------------------
extern "C" void kernel_launch(void* const* d_in, const int* in_sizes, int n_in,
                              void* d_out, int out_size, void* d_ws, size_t ws_size,
                              hipStream_t stream) {
    const float* t       = (const float*)d_in[0]; // (B,S)
    const float* x       = (const float*)d_in[1]; // (B,P,S,D)
    const float* mask    = (const float*)d_in[2]; // (B,P,S)
    const float* alpha_w = (const float*)d_in[3]; // (1,1)
    float* out = (float*)d_out;

    // ws: tpeG (B*S*16 fp32 = 256KB) | E16 (B*S*S bf16 = 4MB)
    float* tpeG = (float*)d_ws;
    unsigned short* E16 = (unsigned short*)((char*)d_ws + (size_t)B_ * S_ * 16 * sizeof(float));

    k_tpe<<<dim3(B_), dim3(256), 0, stream>>>(t, alpha_w, tpeG);
    k_scoresE<<<dim3(S_ / 4, B_), dim3(256), 0, stream>>>(tpeG, E16);
    k_attn3<<<dim3(2, P_, B_), dim3(256), 0, stream>>>(x, mask, E16, out);
}

// Round 4
// 114.045 us; speedup vs baseline: 2.3827x; 1.2507x over previous
//
#include <hip/hip_runtime.h>
#include <math.h>

#define B_ 8
#define P_ 32
#define S_ 512
#define D_ 64

typedef __attribute__((ext_vector_type(8))) short short8;
typedef __attribute__((ext_vector_type(4))) float f32x4;

static __device__ inline unsigned short f2bf(float f) {
    // round-to-nearest-even fp32 -> bf16 (finite inputs only)
    unsigned u = __float_as_uint(f);
    unsigned r = (u + 0x7FFFu + ((u >> 16) & 1u)) >> 16;
    return (unsigned short)r;
}
static __device__ inline float bf2f(unsigned short s) {
    return __uint_as_float(((unsigned)s) << 16);
}

// ---------------------------------------------------------------------------
// Kernel 1 (fully fused): t -> min/max norm -> elu scale -> tpe (transposed,
// in LDS) -> E16[b,r,k] = bf16(exp(score-2)). Grid (64, B) = 512 blocks.
// Each block redundantly computes min/max + all 512 tpe rows (cheap), then
// 4 waves x 2 query rows each produce 8 E16 rows.
// ---------------------------------------------------------------------------
__launch_bounds__(256)
__global__ void k_scoresE2(const float* __restrict__ t, const float* __restrict__ alpha_w,
                           unsigned short* __restrict__ E16) {
    const int b = blockIdx.y;
    const int r0 = blockIdx.x * 8;
    const int tid = threadIdx.x, lane = tid & 63, wave = tid >> 6;

    __shared__ float tpeT[16][S_];   // 32 KB, transposed: [freq][key]
    __shared__ float red[8];

    float v0 = t[b * S_ + tid];
    float v1 = t[b * S_ + tid + 256];
    float mn = fminf(v0, v1), mx = fmaxf(v0, v1);
#pragma unroll
    for (int o = 32; o > 0; o >>= 1) {
        mn = fminf(mn, __shfl_xor(mn, o, 64));
        mx = fmaxf(mx, __shfl_xor(mx, o, 64));
    }
    if (lane == 0) { red[wave] = mn; red[4 + wave] = mx; }
    __syncthreads();
    mn = fminf(fminf(red[0], red[1]), fminf(red[2], red[3]));
    mx = fmaxf(fmaxf(red[4], red[5]), fmaxf(red[6], red[7]));

    float aw = alpha_w[0] * 1000.0f;
    float el = aw > 0.0f ? aw : (__expf(aw) - 1.0f);   // elu, alpha=1
    float inv = (el + 1.0f) / (mx - mn);

    const float divs[8] = {1.0f, 0.31622776601683794f, 0.1f, 0.031622776601683791f,
                           0.01f, 0.0031622776601683794f, 0.001f, 0.00031622776601683794f};
    // rows tid and tid+256; tpe pre-scaled by 0.5 so dot = score/4
    {
        float tn0 = (v0 - mn) * inv;
        float tn1 = (v1 - mn) * inv;
#pragma unroll
        for (int f = 0; f < 8; f++) {
            float a0 = tn0 * divs[f], a1 = tn1 * divs[f];
            tpeT[2 * f][tid]           = 0.5f * __sinf(a0);
            tpeT[2 * f + 1][tid]       = 0.5f * __cosf(a0);
            tpeT[2 * f][tid + 256]     = 0.5f * __sinf(a1);
            tpeT[2 * f + 1][tid + 256] = 0.5f * __cosf(a1);
        }
    }
    __syncthreads();

    const int ra = r0 + wave * 2, rb = ra + 1;
    float qa[16], qb[16];
#pragma unroll
    for (int f = 0; f < 16; f++) { qa[f] = tpeT[f][ra]; qb[f] = tpeT[f][rb]; }

    unsigned* Ea = (unsigned*)(E16 + ((size_t)(b * S_) + ra) * S_);
    unsigned* Eb = (unsigned*)(E16 + ((size_t)(b * S_) + rb) * S_);
#pragma unroll
    for (int j = 0; j < 4; j++) {
        int k0 = j * 128 + lane * 2;
        float a0 = 0.f, a1 = 0.f, b0 = 0.f, b1 = 0.f;
#pragma unroll
        for (int f = 0; f < 16; f++) {
            float2 kv = *(const float2*)&tpeT[f][k0];
            a0 += qa[f] * kv.x; a1 += qa[f] * kv.y;
            b0 += qb[f] * kv.x; b1 += qb[f] * kv.y;
        }
        unsigned ea0 = f2bf(__expf(a0 - 2.0f)), ea1 = f2bf(__expf(a1 - 2.0f));
        unsigned eb0 = f2bf(__expf(b0 - 2.0f)), eb1 = f2bf(__expf(b1 - 2.0f));
        Ea[j * 64 + lane] = ea0 | (ea1 << 16);
        Eb[j * 64 + lane] = eb0 | (eb1 << 16);
    }
}

// ---------------------------------------------------------------------------
// Kernel 2: MFMA attention. Grid 512 (1-D), 512 threads (8 waves).
//   bid>>8 = half (0/1), bid&255 = bp -> blocks of one bp pair on same XCD.
//   copy rows (mask=1): out = x.  query rows (mask=0): softmax via E16.
//   B-operand LDS: XsT[n][k], n=0..63 masked x cols, n=64 mask (denominator
//   falls out of MFMA tile 4 col 0), rows 65..79 zero.
//   KC=64, double-buffered, 1 barrier/chunk, A + x loads prefetched 1 ahead.
// ---------------------------------------------------------------------------
#define KC2 64
#define XSTRIDE 72   // shorts per XsT row (144 B = 36 dwords: b128 conflict-floor)
__launch_bounds__(512, 4)
__global__ void k_attn4(const float* __restrict__ x, const float* __restrict__ mask,
                        const unsigned short* __restrict__ E16, float* __restrict__ out) {
    const int bid = blockIdx.x;
    const int half = bid >> 8;
    const int bp = bid & 255;
    const int b = bp >> 5;
    const int tid = threadIdx.x, lane = tid & 63, wave = tid >> 6;
    const int quad = lane >> 4, nlane = lane & 15;

    __shared__ float maskL[S_];
    __shared__ short kidxL[S_], qidxL[S_];
    __shared__ int cntS[2];
    __shared__ unsigned short XsT[2][80][XSTRIDE];   // 23 KB

    const float* maskBP = mask + (size_t)bp * S_;
    const float* xBP = x + (size_t)bp * S_ * D_;
    float* outBP = out + (size_t)bp * S_ * D_;
    const float4* x4 = (const float4*)xBP;
    float4* out4 = (float4*)outBP;
    const unsigned short* Eb = E16 + (size_t)b * S_ * S_;

    for (int i = tid; i < S_; i += 512) maskL[i] = maskBP[i];
    __syncthreads();

    if (wave == 0) {
        int nk = 0, nq = 0;
        for (int c = 0; c < 8; c++) {
            int tt = c * 64 + lane;
            bool isk = maskL[tt] >= 0.5f;
            unsigned long long bm = __ballot(isk);
            int pb = __popcll(bm & ((1ull << lane) - 1ull));
            if (isk) kidxL[nk + pb] = (short)tt;
            else     qidxL[nq + lane - pb] = (short)tt;
            int c1 = __popcll(bm);
            nk += c1; nq += 64 - c1;
        }
        if (lane == 0) { cntS[0] = nk; cntS[1] = nq; }
    }
    // zero XsT rows 65..79 (both buffers) once
    for (int i = tid; i < 2 * 15 * XSTRIDE; i += 512) {
        int bb = i / (15 * XSTRIDE);
        int rem = i % (15 * XSTRIDE);
        XsT[bb][65 + rem / XSTRIDE][rem % XSTRIDE] = 0;
    }
    __syncthreads();
    const int NK = cntS[0], NQ = cntS[1];

    // ---- copy phase: this block's half of the mask=1 rows ----
    {
        int nkq = (NK + 1) >> 1;
        int j0 = half * nkq, j1 = min(NK, j0 + nkq);
        for (int e = j0 * 16 + tid; e < j1 * 16; e += 512) {
            int s = kidxL[e >> 4];
            int d4 = e & 15;
            out4[s * 16 + d4] = x4[s * 16 + d4];
        }
    }

    // ---- query phase: this block's half of the compacted query list ----
    const int qq = (NQ + 1) >> 1;
    const int qb0 = half * qq;
    const int rows = min(NQ, qb0 + qq) - qb0;
    if (rows <= 0) return;
    const int NT = (rows + 15) >> 4;

    const int tiv0 = wave, tiv1 = wave + 8;
    const bool t0 = tiv0 < NT, t1 = tiv1 < NT;
    const unsigned short* Arow0;
    const unsigned short* Arow1;
    {
        int r0l = min(tiv0 * 16 + nlane, rows - 1);
        Arow0 = Eb + (size_t)qidxL[qb0 + r0l] * S_;
        int r1l = t1 ? min(tiv1 * 16 + nlane, rows - 1) : 0;
        Arow1 = Eb + (size_t)qidxL[qb0 + r1l] * S_;
    }

    const int c64 = tid & 63;   // d column this thread stages
    const int kg = wave;        // 8 keys per thread per chunk
    const float* xcol = xBP + c64;

    auto loadx = [&](int kcv, float* xr) {
        const float* base = xcol + (size_t)(kcv + kg * 8) * D_;
#pragma unroll
        for (int i = 0; i < 8; i++) xr[i] = base[i * D_];
    };
    auto stage = [&](int bufi, int kcv, const float* xr) {
        short8 w8;
#pragma unroll
        for (int i = 0; i < 8; i++) {
            float mv = maskL[kcv + kg * 8 + i];
            w8[i] = (short)f2bf(xr[i] * mv);
        }
        *(short8*)&XsT[bufi][c64][kg * 8] = w8;
        if (tid < KC2) XsT[bufi][64][tid] = f2bf(maskL[kcv + tid]);
    };

    f32x4 acc[2][5];
#pragma unroll
    for (int i = 0; i < 2; i++)
#pragma unroll
        for (int ct = 0; ct < 5; ct++) acc[i][ct] = (f32x4){0.f, 0.f, 0.f, 0.f};

    float xr[8];
    loadx(0, xr);
    stage(0, 0, xr);
    short8 a00 = *(const short8*)(Arow0 + quad * 8);
    short8 a01 = *(const short8*)(Arow0 + 32 + quad * 8);
    short8 a10 = *(const short8*)(Arow1 + quad * 8);
    short8 a11 = *(const short8*)(Arow1 + 32 + quad * 8);
    __syncthreads();

    for (int c = 0; c < 8; c++) {
        const int kc = c * KC2;
        const int cur = c & 1;
        float xrn[8];
        short8 an00, an01, an10, an11;
        if (c < 7) {
            loadx(kc + KC2, xrn);
            an00 = *(const short8*)(Arow0 + kc + KC2 + quad * 8);
            an01 = *(const short8*)(Arow0 + kc + KC2 + 32 + quad * 8);
            an10 = *(const short8*)(Arow1 + kc + KC2 + quad * 8);
            an11 = *(const short8*)(Arow1 + kc + KC2 + 32 + quad * 8);
        }
#pragma unroll
        for (int ct = 0; ct < 5; ct++) {
            short8 b0 = *(const short8*)&XsT[cur][ct * 16 + nlane][quad * 8];
            short8 b1 = *(const short8*)&XsT[cur][ct * 16 + nlane][32 + quad * 8];
            if (t0) {
                acc[0][ct] = __builtin_amdgcn_mfma_f32_16x16x32_bf16(a00, b0, acc[0][ct], 0, 0, 0);
                acc[0][ct] = __builtin_amdgcn_mfma_f32_16x16x32_bf16(a01, b1, acc[0][ct], 0, 0, 0);
            }
            if (t1) {
                acc[1][ct] = __builtin_amdgcn_mfma_f32_16x16x32_bf16(a10, b0, acc[1][ct], 0, 0, 0);
                acc[1][ct] = __builtin_amdgcn_mfma_f32_16x16x32_bf16(a11, b1, acc[1][ct], 0, 0, 0);
            }
        }
        if (c < 7) stage(cur ^ 1, kc + KC2, xrn);
        __syncthreads();
        a00 = an00; a01 = an01; a10 = an10; a11 = an11;
    }

    // ---- epilogue: add self term, normalize, store ----
#pragma unroll
    for (int i = 0; i < 2; i++) {
        const bool ta = (i == 0) ? t0 : t1;
        const int tiv = (i == 0) ? tiv0 : tiv1;
#pragma unroll
        for (int reg = 0; reg < 4; reg++) {
            float den = __shfl(acc[i][4][reg], lane & 48, 64);  // col 0 of tile 4
            int rowl = tiv * 16 + quad * 4 + reg;
            if (ta && rowl < rows) {
                int sg = qidxL[qb0 + rowl];
                float ws = bf2f(Eb[(size_t)sg * (S_ + 1)]);
                float inv = 1.0f / (den + ws);
#pragma unroll
                for (int ct = 0; ct < 4; ct++) {
                    int col = ct * 16 + nlane;
                    float xv = xBP[(size_t)sg * D_ + col];
                    outBP[(size_t)sg * D_ + col] = (acc[i][ct][reg] + ws * xv) * inv;
                }
            }
        }
    }
}

// ---------------------------------------------------------------------------
extern "C" void kernel_launch(void* const* d_in, const int* in_sizes, int n_in,
                              void* d_out, int out_size, void* d_ws, size_t ws_size,
                              hipStream_t stream) {
    const float* t       = (const float*)d_in[0]; // (B,S)
    const float* x       = (const float*)d_in[1]; // (B,P,S,D)
    const float* mask    = (const float*)d_in[2]; // (B,P,S)
    const float* alpha_w = (const float*)d_in[3]; // (1,1)
    float* out = (float*)d_out;

    unsigned short* E16 = (unsigned short*)d_ws;   // B*S*S bf16 = 4 MB

    k_scoresE2<<<dim3(S_ / 8, B_), dim3(256), 0, stream>>>(t, alpha_w, E16);
    k_attn4<<<dim3(512), dim3(512), 0, stream>>>(x, mask, E16, out);
}